// Round 3
// baseline (263.406 us; speedup 1.0000x reference)
//
#include <hip/hip_runtime.h>
#include <math.h>

#define B_    8
#define M_    2048
#define FIN_  256
#define FOUT_ 128
#define ALPHA_ 0.2f
#define NEG_INF_ -9.0e15f

typedef unsigned short u16;
typedef __attribute__((ext_vector_type(8))) short bf16x8;
typedef __attribute__((ext_vector_type(4))) float f32x4;

static __device__ __forceinline__ u16 f2bf(float f) {
  union { float f; unsigned u; } v; v.f = f;
  unsigned r = v.u + 0x7FFFu + ((v.u >> 16) & 1u);   // RNE bf16
  return (u16)(r >> 16);
}

// -------- kernel 0: xbf = bf16(x); Wt[f][k] = bf16(W[k][f]) --------
// blocks 0..2047: x (8 elems/thread). blocks 2048..2175: Wt transpose.
__global__ __launch_bounds__(256) void k_conv(const float* __restrict__ x,
                                              const float* __restrict__ W,
                                              u16* __restrict__ xbf,
                                              u16* __restrict__ Wt) {
  const int blk = blockIdx.x;
  if (blk < 2048) {
    const size_t base = ((size_t)blk * 256 + threadIdx.x) * 8;
    float4 v0 = *(const float4*)(x + base);
    float4 v1 = *(const float4*)(x + base + 4);
    union { u16 u[8]; uint4 q; } o;
    o.u[0] = f2bf(v0.x); o.u[1] = f2bf(v0.y); o.u[2] = f2bf(v0.z); o.u[3] = f2bf(v0.w);
    o.u[4] = f2bf(v1.x); o.u[5] = f2bf(v1.y); o.u[6] = f2bf(v1.z); o.u[7] = f2bf(v1.w);
    *(uint4*)(xbf + base) = o.q;
  } else {
    const int id = (blk - 2048) * 256 + threadIdx.x;   // 32768
    const int f = id >> 8;
    const int k = id & 255;
    Wt[f * FIN_ + k] = f2bf(W[(size_t)k * FOUT_ + f]);
  }
}

// -------- kernel 1: h = x@W via MFMA; fused f1/f2; store h^T bf16 --------
// grid 1024 x 128 thr. Block = 16 rows; wave w owns feats w*64..+63 (ft=4 frags).
__global__ __launch_bounds__(128) void k_xw(const u16* __restrict__ xbf,
                                            const u16* __restrict__ Wt,
                                            const float* __restrict__ a,
                                            u16* __restrict__ ht,
                                            float* __restrict__ f1,
                                            float* __restrict__ f2) {
  int blk = blockIdx.x;
  blk = (blk & 7) * 128 + (blk >> 3);          // XCD swizzle (1024%8==0)
  const int b    = blk >> 7;
  const int row0 = (blk & 127) * 16;           // within batch
  const int rowg = b * M_ + row0;              // global flat row
  const int tid  = threadIdx.x;
  const int w  = tid >> 6;
  const int l  = tid & 63;
  const int lr = l & 15;
  const int g  = l >> 4;
  const int fbase = w * 64;

  f32x4 acc[4];
#pragma unroll
  for (int ft = 0; ft < 4; ++ft) acc[ft] = (f32x4){0.f, 0.f, 0.f, 0.f};

  const u16* xr = xbf + (size_t)(rowg + lr) * FIN_;
#pragma unroll
  for (int ks = 0; ks < 8; ++ks) {
    bf16x8 af = *(const bf16x8*)(xr + ks * 32 + g * 8);
#pragma unroll
    for (int ft = 0; ft < 4; ++ft) {
      bf16x8 bf = *(const bf16x8*)(Wt + (fbase + ft * 16 + lr) * FIN_ + ks * 32 + g * 8);
      acc[ft] = __builtin_amdgcn_mfma_f32_16x16x32_bf16(af, bf, acc[ft], 0, 0, 0);
    }
  }

  // ---- fused f1/f2 (per-wave partial over 64 feats, combine via LDS) ----
  __shared__ float sf1[2][16], sf2[2][16];
  float v1[4] = {0.f, 0.f, 0.f, 0.f};
  float v2[4] = {0.f, 0.f, 0.f, 0.f};
#pragma unroll
  for (int ft = 0; ft < 4; ++ft) {
    const float a1v = a[fbase + ft * 16 + lr];
    const float a2v = a[FOUT_ + fbase + ft * 16 + lr];
#pragma unroll
    for (int j = 0; j < 4; ++j) {
      v1[j] += acc[ft][j] * a1v;
      v2[j] += acc[ft][j] * a2v;
    }
  }
#pragma unroll
  for (int off = 1; off < 16; off <<= 1) {
#pragma unroll
    for (int j = 0; j < 4; ++j) {
      v1[j] += __shfl_xor(v1[j], off);
      v2[j] += __shfl_xor(v2[j], off);
    }
  }
  if (lr == 0) {
#pragma unroll
    for (int j = 0; j < 4; ++j) {
      sf1[w][g * 4 + j] = v1[j];
      sf2[w][g * 4 + j] = v2[j];
    }
  }

  // ---- h^T transpose via LDS ----
  __shared__ float hs[16][132];
#pragma unroll
  for (int ft = 0; ft < 4; ++ft)
#pragma unroll
    for (int j = 0; j < 4; ++j)
      hs[g * 4 + j][fbase + ft * 16 + lr] = acc[ft][j];
  __syncthreads();

  if (tid < 16) {
    f1[rowg + tid] = sf1[0][tid] + sf1[1][tid];
    f2[rowg + tid] = sf2[0][tid] + sf2[1][tid];
  }
  const int f = tid;
  union { u16 u[16]; uint4 q[2]; } hb;
#pragma unroll
  for (int i = 0; i < 16; ++i) hb.u[i] = f2bf(hs[i][f]);
  u16* dst = ht + (size_t)(b * FOUT_ + f) * M_ + row0;
  *(uint4*)(dst)     = hb.q[0];
  *(uint4*)(dst + 8) = hb.q[1];
}

// -------- kernel 2: fused masked-softmax attention, MFMA PV --------
// grid 1024 x 256 thr (4 waves, wave w owns feats w*32..+31). 16 rows/block.
// Score: 16 thr/row (r=tid>>4, ts=tid&15), 8 cols each; adj/f2 software-pipelined.
__global__ __launch_bounds__(256) void k_attn(const u16* __restrict__ ht,
                                              const int* __restrict__ adj,
                                              const float* __restrict__ f1,
                                              const float* __restrict__ f2,
                                              float* __restrict__ out) {
  int blk = blockIdx.x;
  blk = (blk & 7) * 128 + (blk >> 3);         // XCD swizzle (1024%8==0)
  const int b    = blk >> 7;
  const int row0 = (blk & 127) * 16;
  const int tid = threadIdx.x;
  const int w  = tid >> 6;
  const int l  = tid & 63;
  const int lr = l & 15;
  const int g  = l >> 4;
  const int r  = tid >> 4;                    // 16 rows x 16 threads
  const int ts = tid & 15;

  __shared__ __align__(16) u16 P[16][128];    // bf16 P, 16B-slot XOR swizzle
  __shared__ float smx[16], ssum[16], sscale[16], f1s[16];

  if (tid < 16) {
    smx[tid]  = -INFINITY;
    ssum[tid] = 0.f;
    f1s[tid]  = f1[b * M_ + row0 + tid];
  }

  f32x4 acc0 = (f32x4){0.f, 0.f, 0.f, 0.f};
  f32x4 acc1 = (f32x4){0.f, 0.f, 0.f, 0.f};

  const int fbase = w * 32;
  const int* ap   = adj + ((size_t)b * M_ + row0 + r) * M_ + ts * 8;
  const float* fp = f2 + b * M_ + ts * 8;
  const u16* hp0  = ht + (size_t)(b * FOUT_ + fbase + lr) * M_ + g * 8;
  const u16* hp1  = hp0 + 16 * M_;
  char* Pb = (char*)P;

  // prefetch chunk 0
  int4   ajA = *(const int4*)(ap);
  int4   ajB = *(const int4*)(ap + 4);
  float4 fvA = *(const float4*)(fp);
  float4 fvB = *(const float4*)(fp + 4);

  __syncthreads();

  for (int n0 = 0; n0 < M_; n0 += 128) {
    const int   aj[8] = {ajA.x, ajA.y, ajA.z, ajA.w, ajB.x, ajB.y, ajB.z, ajB.w};
    const float fv[8] = {fvA.x, fvA.y, fvA.z, fvA.w, fvB.x, fvB.y, fvB.z, fvB.w};
    if (n0 + 128 < M_) {                      // issue next chunk's loads now
      ajA = *(const int4*)(ap + n0 + 128);
      ajB = *(const int4*)(ap + n0 + 132);
      fvA = *(const float4*)(fp + n0 + 128);
      fvB = *(const float4*)(fp + n0 + 132);
    }
    // ---- scores + online softmax ----
    const float f1r = f1s[r];
    float s[8];
#pragma unroll
    for (int i = 0; i < 8; ++i) {
      float z = f1r + fv[i];
      float e = z > 0.f ? z : ALPHA_ * z;
      s[i] = aj[i] > 0 ? e : NEG_INF_;
    }
    float cmax = s[0];
#pragma unroll
    for (int i = 1; i < 8; ++i) cmax = fmaxf(cmax, s[i]);
#pragma unroll
    for (int off = 1; off < 16; off <<= 1) cmax = fmaxf(cmax, __shfl_xor(cmax, off));
    const float m_old = smx[r];
    const float m_new = fmaxf(m_old, cmax);
    const float scl   = __expf(m_old - m_new);
    float psum = 0.f;
#pragma unroll
    for (int i = 0; i < 8; ++i) {
      float p = __expf(s[i] - m_new);
      s[i] = p;
      psum += p;
    }
#pragma unroll
    for (int off = 1; off < 16; off <<= 1) psum += __shfl_xor(psum, off);
    if (ts == 0) {
      smx[r]    = m_new;
      ssum[r]   = ssum[r] * scl + psum;
      sscale[r] = scl;
    }
    // ---- P -> bf16, swizzled LDS write (1 uint4/thread) ----
    union { u16 u[8]; uint4 q; } pw;
#pragma unroll
    for (int i = 0; i < 8; ++i) pw.u[i] = f2bf(s[i]);
    *(uint4*)(Pb + r * 256 + ((ts ^ (r & 7)) << 4)) = pw.q;
    __syncthreads();

    // ---- MFMA PV: rescale, 8 MFMA per wave ----
    f32x4 scv = { sscale[g * 4], sscale[g * 4 + 1], sscale[g * 4 + 2], sscale[g * 4 + 3] };
    acc0 *= scv;
    acc1 *= scv;
#pragma unroll
    for (int ks = 0; ks < 4; ++ks) {
      bf16x8 af = *(const bf16x8*)(Pb + lr * 256 + (((ks * 4 + g) ^ (lr & 7)) << 4));
      bf16x8 b0 = *(const bf16x8*)(hp0 + n0 + ks * 32);
      bf16x8 b1 = *(const bf16x8*)(hp1 + n0 + ks * 32);
      acc0 = __builtin_amdgcn_mfma_f32_16x16x32_bf16(af, b0, acc0, 0, 0, 0);
      acc1 = __builtin_amdgcn_mfma_f32_16x16x32_bf16(af, b1, acc1, 0, 0, 0);
    }
    __syncthreads();
  }

  // ---- epilogue: 1/sum, ELU, store ----
  f32x4 inv = { 1.f / ssum[g * 4], 1.f / ssum[g * 4 + 1],
                1.f / ssum[g * 4 + 2], 1.f / ssum[g * 4 + 3] };
#pragma unroll
  for (int j = 0; j < 4; ++j) {
    const size_t orow = ((size_t)b * M_ + row0 + g * 4 + j) * FOUT_;
    float t0 = acc0[j] * inv[j];
    float t1 = acc1[j] * inv[j];
    out[orow + fbase + lr]      = t0 > 0.f ? t0 : __expf(t0) - 1.f;
    out[orow + fbase + 16 + lr] = t1 > 0.f ? t1 : __expf(t1) - 1.f;
  }
}

extern "C" void kernel_launch(void* const* d_in, const int* in_sizes, int n_in,
                              void* d_out, int out_size, void* d_ws, size_t ws_size,
                              hipStream_t stream) {
  const float* x   = (const float*)d_in[0];
  const int*   adj = (const int*)d_in[1];
  const float* W   = (const float*)d_in[2];
  const float* a   = (const float*)d_in[3];
  float* out = (float*)d_out;

  char* ws = (char*)d_ws;
  u16*   Wt  = (u16*)ws;                       // 64 KB
  float* f1  = (float*)(ws + 65536);           // 64 KB
  float* f2  = (float*)(ws + 131072);          // 64 KB
  u16*   ht  = (u16*)(ws + 196608);            // 8.4 MB  [B][128][2048] bf16
  u16*   xbf = (u16*)(ws + 196608 + 8388608);  // 8.4 MB  [B*M][256] bf16

  hipLaunchKernelGGL(k_conv, dim3(2176), dim3(256), 0, stream, x, W, xbf, Wt);
  hipLaunchKernelGGL(k_xw,   dim3(1024), dim3(128), 0, stream, xbf, Wt, a, ht, f1, f2);
  hipLaunchKernelGGL(k_attn, dim3(1024), dim3(256), 0, stream, ht, adj, f1, f2, out);
}

// Round 5
// 259.259 us; speedup vs baseline: 1.0160x; 1.0160x over previous
//
#include <hip/hip_runtime.h>
#include <math.h>

#define B_    8
#define M_    2048
#define FIN_  256
#define FOUT_ 128
#define ALPHA_ 0.2f
#define NEG_INF_ -9.0e15f

typedef unsigned short u16;
typedef __attribute__((ext_vector_type(8))) short bf16x8;
typedef __attribute__((ext_vector_type(4))) float f32x4;

static __device__ __forceinline__ u16 f2bf(float f) {
  union { float f; unsigned u; } v; v.f = f;
  unsigned r = v.u + 0x7FFFu + ((v.u >> 16) & 1u);   // RNE bf16
  return (u16)(r >> 16);
}

// -------- kernel 0: Wt[f][k] = bf16(W[k][f])  (128x256) --------
__global__ __launch_bounds__(256) void k_wt(const float* __restrict__ W,
                                            u16* __restrict__ Wt) {
  const int id = blockIdx.x * 256 + threadIdx.x;   // 32768 total
  const int f = id >> 8;
  const int k = id & 255;
  Wt[f * FIN_ + k] = f2bf(W[(size_t)k * FOUT_ + f]);
}

// -------- kernel 1: h = x@W via MFMA (fp32->bf16 in-reg); fused f1/f2; h^T bf16 --------
// grid 1024 x 128 thr. Block = 16 rows; wave w owns feats w*64..+63 (ft=4 frags).
__global__ __launch_bounds__(128) void k_xw(const float* __restrict__ x,
                                            const u16* __restrict__ Wt,
                                            const float* __restrict__ a,
                                            u16* __restrict__ ht,
                                            float* __restrict__ f1,
                                            float* __restrict__ f2) {
  int blk = blockIdx.x;
  blk = (blk & 7) * 128 + (blk >> 3);          // XCD swizzle (1024%8==0)
  const int b    = blk >> 7;
  const int row0 = (blk & 127) * 16;           // within batch
  const int rowg = b * M_ + row0;              // global flat row
  const int tid  = threadIdx.x;
  const int w  = tid >> 6;
  const int l  = tid & 63;
  const int lr = l & 15;
  const int g  = l >> 4;
  const int fbase = w * 64;

  f32x4 acc[4];
#pragma unroll
  for (int ft = 0; ft < 4; ++ft) acc[ft] = (f32x4){0.f, 0.f, 0.f, 0.f};

  const float* xr = x + (size_t)(rowg + lr) * FIN_;
#pragma unroll
  for (int ks = 0; ks < 8; ++ks) {
    float4 xa = *(const float4*)(xr + ks * 32 + g * 8);
    float4 xc = *(const float4*)(xr + ks * 32 + g * 8 + 4);
    bf16x8 af;
    af[0] = (short)f2bf(xa.x); af[1] = (short)f2bf(xa.y);
    af[2] = (short)f2bf(xa.z); af[3] = (short)f2bf(xa.w);
    af[4] = (short)f2bf(xc.x); af[5] = (short)f2bf(xc.y);
    af[6] = (short)f2bf(xc.z); af[7] = (short)f2bf(xc.w);
#pragma unroll
    for (int ft = 0; ft < 4; ++ft) {
      bf16x8 bf = *(const bf16x8*)(Wt + (fbase + ft * 16 + lr) * FIN_ + ks * 32 + g * 8);
      acc[ft] = __builtin_amdgcn_mfma_f32_16x16x32_bf16(af, bf, acc[ft], 0, 0, 0);
    }
  }

  // ---- fused f1/f2 (per-wave partial over 64 feats, combine via LDS) ----
  __shared__ float sf1[2][16], sf2[2][16];
  float v1[4] = {0.f, 0.f, 0.f, 0.f};
  float v2[4] = {0.f, 0.f, 0.f, 0.f};
#pragma unroll
  for (int ft = 0; ft < 4; ++ft) {
    const float a1v = a[fbase + ft * 16 + lr];
    const float a2v = a[FOUT_ + fbase + ft * 16 + lr];
#pragma unroll
    for (int j = 0; j < 4; ++j) {
      v1[j] += acc[ft][j] * a1v;
      v2[j] += acc[ft][j] * a2v;
    }
  }
#pragma unroll
  for (int off = 1; off < 16; off <<= 1) {
#pragma unroll
    for (int j = 0; j < 4; ++j) {
      v1[j] += __shfl_xor(v1[j], off);
      v2[j] += __shfl_xor(v2[j], off);
    }
  }
  if (lr == 0) {
#pragma unroll
    for (int j = 0; j < 4; ++j) {
      sf1[w][g * 4 + j] = v1[j];
      sf2[w][g * 4 + j] = v2[j];
    }
  }

  // ---- h^T transpose via LDS ----
  __shared__ float hs[16][132];
#pragma unroll
  for (int ft = 0; ft < 4; ++ft)
#pragma unroll
    for (int j = 0; j < 4; ++j)
      hs[g * 4 + j][fbase + ft * 16 + lr] = acc[ft][j];
  __syncthreads();

  if (tid < 16) {
    f1[rowg + tid] = sf1[0][tid] + sf1[1][tid];
    f2[rowg + tid] = sf2[0][tid] + sf2[1][tid];
  }
  const int f = tid;
  union { u16 u[16]; uint4 q[2]; } hb;
#pragma unroll
  for (int i = 0; i < 16; ++i) hb.u[i] = f2bf(hs[i][f]);
  u16* dst = ht + (size_t)(b * FOUT_ + f) * M_ + row0;
  *(uint4*)(dst)     = hb.q[0];
  *(uint4*)(dst + 8) = hb.q[1];
}

// -------- kernel 2: fused masked-softmax attention, MFMA PV --------
// grid 1024 x 256 thr (4 waves, wave w owns feats w*32..+31). 16 rows/block.
// ONE barrier/iter; P AND sscale double-buffered (sscale race was the R4 bug);
// adj/f2/V prefetched a full iteration ahead.
__global__ __launch_bounds__(256) void k_attn(const u16* __restrict__ ht,
                                              const int* __restrict__ adj,
                                              const float* __restrict__ f1,
                                              const float* __restrict__ f2,
                                              float* __restrict__ out) {
  int blk = blockIdx.x;
  blk = (blk & 7) * 128 + (blk >> 3);         // XCD swizzle (1024%8==0)
  const int b    = blk >> 7;
  const int row0 = (blk & 127) * 16;
  const int tid = threadIdx.x;
  const int w  = tid >> 6;
  const int l  = tid & 63;
  const int lr = l & 15;
  const int g  = l >> 4;
  const int r  = tid >> 4;                    // 16 rows x 16 threads
  const int ts = tid & 15;

  __shared__ __align__(16) u16 P[2][16][128];  // double-buffered bf16 P, XOR swizzle
  __shared__ float sscale[2][16];              // double-buffered rescale factor
  __shared__ float smx[16], ssum[16], f1s[16];

  if (tid < 16) {
    smx[tid]  = -INFINITY;
    ssum[tid] = 0.f;
    f1s[tid]  = f1[b * M_ + row0 + tid];
  }

  f32x4 acc0 = (f32x4){0.f, 0.f, 0.f, 0.f};
  f32x4 acc1 = (f32x4){0.f, 0.f, 0.f, 0.f};

  const int fbase = w * 32;
  const int* ap   = adj + ((size_t)b * M_ + row0 + r) * M_ + ts * 8;
  const float* fp = f2 + b * M_ + ts * 8;
  const u16* hp0  = ht + (size_t)(b * FOUT_ + fbase + lr) * M_ + g * 8;
  const u16* hp1  = hp0 + 16 * M_;
  char* Pb = (char*)P;

  // prefetch chunk 0: adj, f2, V
  int4   ajA = *(const int4*)(ap);
  int4   ajB = *(const int4*)(ap + 4);
  float4 fvA = *(const float4*)(fp);
  float4 fvB = *(const float4*)(fp + 4);
  bf16x8 vbuf0[8], vbuf1[8];
#pragma unroll
  for (int ks = 0; ks < 4; ++ks) {
    vbuf0[ks]     = *(const bf16x8*)(hp0 + ks * 32);
    vbuf0[4 + ks] = *(const bf16x8*)(hp1 + ks * 32);
  }

  __syncthreads();

  auto iter = [&](int it, bf16x8 (&vcur)[8], bf16x8 (&vnxt)[8]) {
    const int n0 = it * 128;
    const int bi = it & 1;
    // ---- scores + online softmax from prefetched regs ----
    const int   aj[8] = {ajA.x, ajA.y, ajA.z, ajA.w, ajB.x, ajB.y, ajB.z, ajB.w};
    const float fv[8] = {fvA.x, fvA.y, fvA.z, fvA.w, fvB.x, fvB.y, fvB.z, fvB.w};
    const float f1r = f1s[r];
    float s[8];
#pragma unroll
    for (int i = 0; i < 8; ++i) {
      float z = f1r + fv[i];
      float e = z > 0.f ? z : ALPHA_ * z;
      s[i] = aj[i] > 0 ? e : NEG_INF_;
    }
    float cmax = s[0];
#pragma unroll
    for (int i = 1; i < 8; ++i) cmax = fmaxf(cmax, s[i]);
#pragma unroll
    for (int off = 1; off < 16; off <<= 1) cmax = fmaxf(cmax, __shfl_xor(cmax, off));
    const float m_old = smx[r];
    const float m_new = fmaxf(m_old, cmax);
    const float scl   = __expf(m_old - m_new);
    float psum = 0.f;
#pragma unroll
    for (int i = 0; i < 8; ++i) {
      float p = __expf(s[i] - m_new);
      s[i] = p;
      psum += p;
    }
#pragma unroll
    for (int off = 1; off < 16; off <<= 1) psum += __shfl_xor(psum, off);
    if (ts == 0) {
      smx[r]       = m_new;
      ssum[r]      = ssum[r] * scl + psum;
      sscale[bi][r] = scl;
    }
    // ---- P -> bf16, swizzled LDS write into buffer bi ----
    union { u16 u[8]; uint4 q; } pw;
#pragma unroll
    for (int i = 0; i < 8; ++i) pw.u[i] = f2bf(s[i]);
    *(uint4*)(Pb + bi * 4096 + r * 256 + ((ts ^ (r & 7)) << 4)) = pw.q;
    __syncthreads();   // ONE barrier per iteration

    // ---- issue next chunk's loads (drain at NEXT barrier, a full iter away) ----
    const int nn = (it + 1 < 16) ? (n0 + 128) : 0;   // harmless tail reload
    ajA = *(const int4*)(ap + nn);
    ajB = *(const int4*)(ap + nn + 4);
    fvA = *(const float4*)(fp + nn);
    fvB = *(const float4*)(fp + nn + 4);
#pragma unroll
    for (int ks = 0; ks < 4; ++ks) {
      vnxt[ks]     = *(const bf16x8*)(hp0 + nn + ks * 32);
      vnxt[4 + ks] = *(const bf16x8*)(hp1 + nn + ks * 32);
    }
    // ---- MFMA PV from current regs + P[bi] ----
    f32x4 scv = { sscale[bi][g * 4],     sscale[bi][g * 4 + 1],
                  sscale[bi][g * 4 + 2], sscale[bi][g * 4 + 3] };
    acc0 *= scv;
    acc1 *= scv;
#pragma unroll
    for (int ks = 0; ks < 4; ++ks) {
      bf16x8 af = *(const bf16x8*)(Pb + bi * 4096 + lr * 256 +
                                   (((ks * 4 + g) ^ (lr & 7)) << 4));
      acc0 = __builtin_amdgcn_mfma_f32_16x16x32_bf16(af, vcur[ks],     acc0, 0, 0, 0);
      acc1 = __builtin_amdgcn_mfma_f32_16x16x32_bf16(af, vcur[4 + ks], acc1, 0, 0, 0);
    }
  };

#pragma unroll 1
  for (int it = 0; it < 16; it += 2) {
    iter(it,     vbuf0, vbuf1);
    iter(it + 1, vbuf1, vbuf0);
  }

  // ---- epilogue: 1/sum, ELU, store ----
  f32x4 inv = { 1.f / ssum[g * 4], 1.f / ssum[g * 4 + 1],
                1.f / ssum[g * 4 + 2], 1.f / ssum[g * 4 + 3] };
#pragma unroll
  for (int j = 0; j < 4; ++j) {
    const size_t orow = ((size_t)b * M_ + row0 + g * 4 + j) * FOUT_;
    float t0 = acc0[j] * inv[j];
    float t1 = acc1[j] * inv[j];
    out[orow + fbase + lr]      = t0 > 0.f ? t0 : __expf(t0) - 1.f;
    out[orow + fbase + 16 + lr] = t1 > 0.f ? t1 : __expf(t1) - 1.f;
  }
}

extern "C" void kernel_launch(void* const* d_in, const int* in_sizes, int n_in,
                              void* d_out, int out_size, void* d_ws, size_t ws_size,
                              hipStream_t stream) {
  const float* x   = (const float*)d_in[0];
  const int*   adj = (const int*)d_in[1];
  const float* W   = (const float*)d_in[2];
  const float* a   = (const float*)d_in[3];
  float* out = (float*)d_out;

  char* ws = (char*)d_ws;
  u16*   Wt = (u16*)ws;                        // 64 KB
  float* f1 = (float*)(ws + 65536);            // 64 KB
  float* f2 = (float*)(ws + 131072);           // 64 KB
  u16*   ht = (u16*)(ws + 196608);             // 8.4 MB  [B][128][2048] bf16

  hipLaunchKernelGGL(k_wt,   dim3(128),  dim3(256), 0, stream, W, Wt);
  hipLaunchKernelGGL(k_xw,   dim3(1024), dim3(128), 0, stream, x, Wt, a, ht, f1, f2);
  hipLaunchKernelGGL(k_attn, dim3(1024), dim3(256), 0, stream, ht, adj, f1, f2, out);
}